// Round 23
// baseline (188.127 us; speedup 1.0000x reference)
//
#include <hip/hip_runtime.h>

#define H_ 8
#define DK 64
#define LQ 2048
#define LK 2048
#define BS 2
#define DM 512

typedef _Float16 f16;
typedef _Float16 f16x8 __attribute__((ext_vector_type(8)));
typedef float f32x4 __attribute__((ext_vector_type(4)));
typedef unsigned long long u64;

#define LS 72   // f16 LDS row stride (144B)
#define PS 40   // f16 LDS row stride for P half-tiles
#define RS 48   // R row stride (f32)

#define NQKV 1536  // qkv blocks in merged kernel; maskpack blocks follow

// Q projection prescale: 1/sqrt(64) * log2(e)  (exp -> exp2 in attn)
#define QSCALE 0.1803368801111204f

// ---------------- prep: W transpose (blocks 0..255) + rpe cvt (block 256) ----------------
__global__ __launch_bounds__(256) void prep_k(const float* __restrict__ Wq,
                                              const float* __restrict__ Wk,
                                              const float* __restrict__ Wv,
                                              const float* __restrict__ Wo,
                                              f16* __restrict__ WT,
                                              const float* __restrict__ rpe,
                                              f16* __restrict__ rpef) {
  __shared__ f16 T[64][LS];
  const int bid = blockIdx.x, tid = threadIdx.x;
  if (bid == 256) {  // ---- rpe cvt+pad: [33][64] f32 -> [48][64] f16 ----
#pragma unroll
    for (int j = 0; j < 12; j++) {
      int idx = tid + j * 256;
      int row = idx >> 6, d = idx & 63;
      rpef[idx] = row < 33 ? (f16)rpe[row * DK + d] : (f16)0.f;
    }
    return;
  }
  // ---- wtr: W[k][n] f32 -> WT[seg][n][k] f16 ----
  const int z = bid >> 6, rem = bid & 63;
  const float* W = z == 0 ? Wq : (z == 1 ? Wk : (z == 2 ? Wv : Wo));
  const int n0 = (rem & 7) * 64, k0 = (rem >> 3) * 64;
  const int r = tid >> 2, cg = tid & 3;
#pragma unroll
  for (int p = 0; p < 4; p++) {
    f32x4 v = *(const f32x4*)(W + (size_t)(k0 + r) * DM + n0 + cg * 16 + p * 4);
#pragma unroll
    for (int j = 0; j < 4; j++) T[cg * 16 + p * 4 + j][r] = (f16)v[j];
  }
  __syncthreads();
  const int n = tid >> 2, kc = tid & 3;
#pragma unroll
  for (int p = 0; p < 2; p++) {
    *(f16x8*)(WT + ((size_t)z * DM + n0 + n) * DM + k0 + kc * 16 + p * 8) =
        *(const f16x8*)&T[n][kc * 16 + p * 8];
  }
}

// ---------------- merged: fused QKV projection GEMM + relR epilogue + maskpack ----------------
__global__ __launch_bounds__(256, 4) void qkvm_k(
    const float* __restrict__ qin, const float* __restrict__ kin, const float* __restrict__ vin,
    const f16* __restrict__ WT, const f16* __restrict__ rpef,
    const float* __restrict__ bq, const float* __restrict__ bk, const float* __restrict__ bv,
    f16* __restrict__ qp, f16* __restrict__ kp, f16* __restrict__ vpt,
    float* __restrict__ R, const int* __restrict__ mask, u64* __restrict__ mp64) {
  const int tid = threadIdx.x;
  if (blockIdx.x >= NQKV) {  // ---- maskpack blocks ----
    size_t t = (size_t)(blockIdx.x - NQKV) * 256 + tid;
    u64 bits = __ballot(mask[t] != 0);
    if ((tid & 63) == 0) mp64[t >> 6] = bits;
    return;
  }
  __shared__ f16 As[64][LS];
  __shared__ f16 Bt[64][LS];
  const int lane = tid & 63, w = tid >> 6;
  const int wr = w >> 1, wc = w & 1, fr = lane & 15, fs = lane >> 4;
  const int m0 = (blockIdx.x & 63) * 64;
  const int n0g = (blockIdx.x >> 6) * 64, seg = n0g >> 9, nn0 = n0g & 511;
  const float* X = seg == 0 ? qin : (seg == 1 ? kin : vin);
  const f16* WTs = WT + (size_t)seg * DM * DM;
  const float* bias = seg == 0 ? bq : (seg == 1 ? bk : bv);
  const float scale = seg == 0 ? QSCALE : 1.0f;

  f32x4 acc[2][2] = {};

  for (int k0 = 0; k0 < DM; k0 += 64) {
    __syncthreads();
    {
      int m = tid >> 2, c0 = tid & 3;
#pragma unroll
      for (int pp = 0; pp < 2; pp++) {
        int cc = c0 + pp * 4;
        const float* p = X + (size_t)(m0 + m) * DM + k0 + cc * 8;
        f32x4 v0 = *(const f32x4*)p;
        f32x4 v1 = *(const f32x4*)(p + 4);
        f16x8 hv;
#pragma unroll
        for (int i = 0; i < 4; i++) { hv[i] = (f16)v0[i]; hv[i + 4] = (f16)v1[i]; }
        *(f16x8*)&As[m][cc * 8] = hv;
      }
      int n = tid >> 2, kc = tid & 3;
#pragma unroll
      for (int pp = 0; pp < 2; pp++) {
        *(f16x8*)&Bt[n][kc * 16 + pp * 8] =
            *(const f16x8*)(WTs + (size_t)(nn0 + n) * DM + k0 + kc * 16 + pp * 8);
      }
    }
    __syncthreads();
#pragma unroll
    for (int kc = 0; kc < 2; kc++) {
      f16x8 a[2], b[2];
#pragma unroll
      for (int mi = 0; mi < 2; mi++)
        a[mi] = *(const f16x8*)&As[wr * 32 + mi * 16 + fr][kc * 32 + fs * 8];
#pragma unroll
      for (int ni = 0; ni < 2; ni++)
        b[ni] = *(const f16x8*)&Bt[wc * 32 + ni * 16 + fr][kc * 32 + fs * 8];
#pragma unroll
      for (int mi = 0; mi < 2; mi++)
#pragma unroll
        for (int ni = 0; ni < 2; ni++)
          acc[mi][ni] = __builtin_amdgcn_mfma_f32_16x16x32_f16(a[mi], b[ni], acc[mi][ni], 0, 0, 0);
    }
  }

  const int h = nn0 >> 6, b_ = m0 >> 11, l0 = m0 & (LQ - 1);
  if (seg < 2) {
    f16* out = seg == 0 ? qp : kp;
    if (seg == 0) __syncthreads();
#pragma unroll
    for (int mi = 0; mi < 2; mi++)
#pragma unroll
      for (int ni = 0; ni < 2; ni++) {
        int d = wc * 32 + ni * 16 + fr;
        float bb = bias[nn0 + d];
#pragma unroll
        for (int i = 0; i < 4; i++) {
          int row = wr * 32 + mi * 16 + fs * 4 + i;
          f16 hv = (f16)((acc[mi][ni][i] + bb) * scale);
          out[((size_t)(b_ * H_ + h) * LQ + l0 + row) * DK + d] = hv;
          if (seg == 0) As[row][d] = hv;
        }
      }
    if (seg == 0) {
      __syncthreads();
      f16x8 a0 = *(const f16x8*)&As[w * 16 + fr][fs * 8];
      f16x8 a1 = *(const f16x8*)&As[w * 16 + fr][32 + fs * 8];
      const size_t rbase = ((size_t)(b_ * H_ + h) * LQ + l0 + w * 16);
#pragma unroll
      for (int nt = 0; nt < 3; nt++) {
        f16x8 b0 = *(const f16x8*)(rpef + (size_t)(nt * 16 + fr) * DK + fs * 8);
        f16x8 b1 = *(const f16x8*)(rpef + (size_t)(nt * 16 + fr) * DK + 32 + fs * 8);
        f32x4 rc = {};
        rc = __builtin_amdgcn_mfma_f32_16x16x32_f16(a0, b0, rc, 0, 0, 0);
        rc = __builtin_amdgcn_mfma_f32_16x16x32_f16(a1, b1, rc, 0, 0, 0);
#pragma unroll
        for (int i = 0; i < 4; i++)
          R[(rbase + fs * 4 + i) * RS + nt * 16 + fr] = rc[i];
      }
    }
  } else {
    __syncthreads();
#pragma unroll
    for (int mi = 0; mi < 2; mi++)
#pragma unroll
      for (int ni = 0; ni < 2; ni++) {
        int d = wc * 32 + ni * 16 + fr;
        float bb = bias[nn0 + d];
#pragma unroll
        for (int i = 0; i < 4; i++) {
          int ml = wr * 32 + mi * 16 + fs * 4 + i;
          As[d][ml] = (f16)(acc[mi][ni][i] + bb);
        }
      }
    __syncthreads();
    int r = tid >> 2;
#pragma unroll
    for (int pp = 0; pp < 2; pp++) {
      int c = (tid & 3) + pp * 4;
      *(f16x8*)(vpt + ((size_t)((b_ * H_ + h) * DK + r)) * LK + l0 + c * 8) =
          *(const f16x8*)&As[r][c * 8];
    }
  }
}

// ---------------- fused attention: sweep1 KBLK=256 (XOR-swizzled K1), sweep2 KBLK=64 ----
__global__ __launch_bounds__(512, 4) void attn_k(const f16* __restrict__ qp,
                                                 const f16* __restrict__ kp,
                                                 const f16* __restrict__ vpt,
                                                 const float* __restrict__ R,
                                                 const unsigned* __restrict__ mp,
                                                 float* __restrict__ attn,
                                                 f16* __restrict__ concat) {
  __shared__ union {
    struct {
      f16 Ks[64][LS];       // sweep-2 K tile
      f16 Vt[64][LS];       // sweep-2 V tile
      float Oc[4][16][68];  // epilogue combine
    } m;                     // 35840 B
    f16 K1[256][64];         // sweep-1: 256 K rows, XOR-chunk swizzle (32768 B)
  } U;
  __shared__ f16 Pl[8][16][PS];  // per-wave P half-tile
  __shared__ float Rl[64][34];
  __shared__ float Ph[2][64];
  const int tid = threadIdx.x, lane = tid & 63, w = tid >> 6;
  const int wq = w & 3, wh = w >> 2;
  const int fr = lane & 15, fs = lane >> 4;
  const int flat = blockIdx.x;
  const int idx = flat >> 3;
  const int bh = (flat & 7) * 2 + (idx >> 5), q0 = (idx & 31) * 64;
  const int b = bh >> 3, h = bh & 7;
  const f16* Qb = qp + ((size_t)bh * LQ + q0) * DK;
  const f16* Kb = kp + (size_t)bh * LQ * DK;
  const f16* Vb = vpt + (size_t)bh * DK * LK;

  for (int i2 = tid; i2 < 64 * 34; i2 += 512)
    Rl[i2 / 34][i2 % 34] = R[((size_t)bh * LQ + q0 + i2 / 34) * RS + i2 % 34];
  __syncthreads();

  f16x8 qa[2];
#pragma unroll
  for (int h2 = 0; h2 < 2; h2++)
    qa[h2] = *(const f16x8*)(Qb + (size_t)(wq * 16 + fr) * DK + h2 * 32 + fs * 8);

  int qq[4];
  float rlo[4], rhi[4];
  const unsigned* mprow[4];
#pragma unroll
  for (int i = 0; i < 4; i++) {
    qq[i] = wq * 16 + fs * 4 + i;
    rlo[i] = Rl[qq[i]][0];
    rhi[i] = Rl[qq[i]][32];
    mprow[i] = mp + ((size_t)b * LQ + q0 + qq[i]) * 64;
  }

  // ---- sweep 1: denominator (KBLK=256: 8 visits, 16 barriers total) ----
  float psum[4] = {0.f, 0.f, 0.f, 0.f};
  {
    const int r8 = tid >> 3, c8 = tid & 7;
    const int sc8 = (c8 ^ (r8 & 7)) * 8;  // swizzled chunk (row low bits invariant over +64)
    for (int kt = 0; kt < LK; kt += 256) {
      __syncthreads();
#pragma unroll
      for (int g = 0; g < 4; g++) {
        int row = g * 64 + r8;
        *(f16x8*)&U.K1[row][sc8] = *(const f16x8*)(Kb + (size_t)(kt + row) * DK + c8 * 8);
      }
      __syncthreads();
#pragma unroll
      for (int qtr = 0; qtr < 4; qtr++) {
        const int kb = kt + qtr * 64;
        f32x4 sv[2];
#pragma unroll
        for (int cbh = 0; cbh < 2; cbh++) {
          int row = qtr * 64 + (wh * 2 + cbh) * 16 + fr;
          f32x4 s = {};
#pragma unroll
          for (int h2 = 0; h2 < 2; h2++) {
            f16x8 bf = *(const f16x8*)&U.K1[row][((h2 * 4 + fs) ^ (row & 7)) * 8];
            s = __builtin_amdgcn_mfma_f32_16x16x32_f16(qa[h2], bf, s, 0, 0, 0);
          }
          sv[cbh] = s;
        }
        unsigned mw[4];
#pragma unroll
        for (int i = 0; i < 4; i++) mw[i] = mprow[i][(kb >> 5) + wh];
        const int dt = kb - q0;
        if (dt <= -128 || dt >= 128) {
#pragma unroll
          for (int cbh = 0; cbh < 2; cbh++)
#pragma unroll
            for (int i = 0; i < 4; i++) {
              float sc = sv[cbh][i] + (dt < 0 ? rlo[i] : rhi[i]);
              psum[i] += ((mw[i] >> (cbh * 16 + fr)) & 1u) ? exp2f(sc) : 0.f;
            }
        } else {
#pragma unroll
          for (int cbh = 0; cbh < 2; cbh++)
#pragma unroll
            for (int i = 0; i < 4; i++) {
              int dd = dt + wh * 32 + cbh * 16 + fr - qq[i];
              dd = dd < -16 ? -16 : (dd > 16 ? 16 : dd);
              float sc = sv[cbh][i] + Rl[qq[i]][dd + 16];
              psum[i] += ((mw[i] >> (cbh * 16 + fr)) & 1u) ? exp2f(sc) : 0.f;
            }
        }
      }
    }
  }
#pragma unroll
  for (int i = 0; i < 4; i++) {
    float v = psum[i];
    v += __shfl_xor(v, 1);
    v += __shfl_xor(v, 2);
    v += __shfl_xor(v, 4);
    v += __shfl_xor(v, 8);
    psum[i] = v;
  }
  if (fr == 0)
#pragma unroll
    for (int i = 0; i < 4; i++) Ph[wh][qq[i]] = psum[i];
  __syncthreads();
  float inv[4];
#pragma unroll
  for (int i = 0; i < 4; i++) inv[i] = 1.f / (Ph[0][qq[i]] + Ph[1][qq[i]]);

  // ---- sweep 2: recompute, write normalized attn, accumulate PV (KBLK=64) ----
  f32x4 oacc[4] = {};
  for (int kt = 0; kt < LK; kt += 64) {
    __syncthreads();
    {
      int r = tid >> 3, c = tid & 7;
      *(f16x8*)&U.m.Ks[r][c * 8] = *(const f16x8*)(Kb + (size_t)(kt + r) * DK + c * 8);
      *(f16x8*)&U.m.Vt[r][c * 8] = *(const f16x8*)(Vb + (size_t)r * LK + kt + c * 8);
    }
    __syncthreads();
    f32x4 sv[2];
#pragma unroll
    for (int cbh = 0; cbh < 2; cbh++) {
      int cb = wh * 2 + cbh;
      f32x4 s = {};
#pragma unroll
      for (int h2 = 0; h2 < 2; h2++) {
        f16x8 bf = *(const f16x8*)&U.m.Ks[cb * 16 + fr][h2 * 32 + fs * 8];
        s = __builtin_amdgcn_mfma_f32_16x16x32_f16(qa[h2], bf, s, 0, 0, 0);
      }
      sv[cbh] = s;
    }
    unsigned mw[4];
#pragma unroll
    for (int i = 0; i < 4; i++) mw[i] = mprow[i][(kt >> 5) + wh];
    const int dt = kt - q0;
    if (dt <= -128 || dt >= 128) {
#pragma unroll
      for (int cbh = 0; cbh < 2; cbh++)
#pragma unroll
        for (int i = 0; i < 4; i++) {
          float sc = sv[cbh][i] + (dt < 0 ? rlo[i] : rhi[i]);
          float pv = ((mw[i] >> (cbh * 16 + fr)) & 1u) ? exp2f(sc) * inv[i] : 0.f;
          Pl[w][fs * 4 + i][cbh * 16 + fr] = (f16)pv;
        }
    } else {
#pragma unroll
      for (int cbh = 0; cbh < 2; cbh++)
#pragma unroll
        for (int i = 0; i < 4; i++) {
          int dd = dt + wh * 32 + cbh * 16 + fr - qq[i];
          dd = dd < -16 ? -16 : (dd > 16 ? 16 : dd);
          float sc = sv[cbh][i] + Rl[qq[i]][dd + 16];
          float pv = ((mw[i] >> (cbh * 16 + fr)) & 1u) ? exp2f(sc) * inv[i] : 0.f;
          Pl[w][fs * 4 + i][cbh * 16 + fr] = (f16)pv;
        }
    }
    // PV over this wave's 32-k half (wave-private Pl)
    {
      f16x8 pa = *(const f16x8*)&Pl[w][fr][fs * 8];
#pragma unroll
      for (int db = 0; db < 4; db++) {
        f16x8 vb = *(const f16x8*)&U.m.Vt[db * 16 + fr][wh * 32 + fs * 8];
        oacc[db] = __builtin_amdgcn_mfma_f32_16x16x32_f16(pa, vb, oacc[db], 0, 0, 0);
      }
    }
    // coalesced attn write from Pl (f32x4, non-temporal)
    {
      int r2 = lane >> 2, cq = lane & 3;
      float* arow = attn + ((size_t)bh * LQ + q0 + wq * 16 + r2) * LK + kt + wh * 32 + cq * 8;
      f16x8 pv8 = *(const f16x8*)&Pl[w][r2][cq * 8];
      f32x4 o0 = {(float)pv8[0], (float)pv8[1], (float)pv8[2], (float)pv8[3]};
      f32x4 o1 = {(float)pv8[4], (float)pv8[5], (float)pv8[6], (float)pv8[7]};
      __builtin_nontemporal_store(o0, (f32x4*)arow);
      __builtin_nontemporal_store(o1, (f32x4*)(arow + 4));
    }
  }

  // combine oacc across k-halves, write concat (f16 [b, l, h*64+d])
  __syncthreads();
  if (wh == 1) {
#pragma unroll
    for (int db = 0; db < 4; db++)
#pragma unroll
      for (int i = 0; i < 4; i++) U.m.Oc[wq][fs * 4 + i][db * 16 + fr] = oacc[db][i];
  }
  __syncthreads();
  if (wh == 0) {
#pragma unroll
    for (int db = 0; db < 4; db++)
#pragma unroll
      for (int i = 0; i < 4; i++) {
        float val = oacc[db][i] + U.m.Oc[wq][fs * 4 + i][db * 16 + fr];
        int gq = q0 + wq * 16 + fs * 4 + i;
        concat[((size_t)b * LQ + gq) * DM + h * DK + db * 16 + fr] = (f16)val;
      }
  }
}

// ---------------- output GEMM (B from WT seg 3, plain stores) ------
__global__ __launch_bounds__(256, 4) void ogemm_k(const f16* __restrict__ X,
                                                  const f16* __restrict__ WT,
                                                  const float* __restrict__ bias,
                                                  float* __restrict__ out) {
  __shared__ f16 As[64][LS];
  __shared__ f16 Bt[64][LS];
  const int tid = threadIdx.x, lane = tid & 63, w = tid >> 6;
  const int wr = w >> 1, wc = w & 1, fr = lane & 15, fs = lane >> 4;
  const int m0 = blockIdx.x * 64, n0 = blockIdx.y * 64;
  const f16* WTo = WT + (size_t)3 * DM * DM;

  f32x4 acc[2][2] = {};
  for (int k0 = 0; k0 < DM; k0 += 64) {
    __syncthreads();
    {
      int r = tid >> 2, c0 = tid & 3;
#pragma unroll
      for (int pp = 0; pp < 2; pp++) {
        int c = c0 + pp * 4;
        *(f16x8*)&As[r][c * 8] = *(const f16x8*)(X + (size_t)(m0 + r) * DM + k0 + c * 8);
      }
      int n = tid >> 2, kc = tid & 3;
#pragma unroll
      for (int pp = 0; pp < 2; pp++) {
        *(f16x8*)&Bt[n][kc * 16 + pp * 8] =
            *(const f16x8*)(WTo + (size_t)(n0 + n) * DM + k0 + kc * 16 + pp * 8);
      }
    }
    __syncthreads();
#pragma unroll
    for (int kc = 0; kc < 2; kc++) {
      f16x8 a[2], b[2];
#pragma unroll
      for (int mi = 0; mi < 2; mi++)
        a[mi] = *(const f16x8*)&As[wr * 32 + mi * 16 + fr][kc * 32 + fs * 8];
#pragma unroll
      for (int ni = 0; ni < 2; ni++)
        b[ni] = *(const f16x8*)&Bt[wc * 32 + ni * 16 + fr][kc * 32 + fs * 8];
#pragma unroll
      for (int mi = 0; mi < 2; mi++)
#pragma unroll
        for (int ni = 0; ni < 2; ni++)
          acc[mi][ni] = __builtin_amdgcn_mfma_f32_16x16x32_f16(a[mi], b[ni], acc[mi][ni], 0, 0, 0);
    }
  }
#pragma unroll
  for (int mi = 0; mi < 2; mi++)
#pragma unroll
    for (int ni = 0; ni < 2; ni++) {
      int gcol = n0 + wc * 32 + ni * 16 + fr;
      float bb = bias[gcol];
#pragma unroll
      for (int i = 0; i < 4; i++) {
        int grow = m0 + wr * 32 + mi * 16 + fs * 4 + i;
        out[(size_t)grow * DM + gcol] = acc[mi][ni][i] + bb;
      }
    }
}

extern "C" void kernel_launch(void* const* d_in, const int* in_sizes, int n_in,
                              void* d_out, int out_size, void* d_ws, size_t ws_size,
                              hipStream_t stream) {
  const float* q = (const float*)d_in[0];
  const float* k = (const float*)d_in[1];
  const float* v = (const float*)d_in[2];
  const int* mask = (const int*)d_in[3];
  const float* Wq = (const float*)d_in[4];
  const float* bq = (const float*)d_in[5];
  const float* Wk = (const float*)d_in[6];
  const float* bk = (const float*)d_in[7];
  const float* Wv = (const float*)d_in[8];
  const float* bv = (const float*)d_in[9];
  const float* Wo = (const float*)d_in[10];
  const float* bo = (const float*)d_in[11];
  const float* rpe = (const float*)d_in[12];

  char* ws = (char*)d_ws;
  f16* qp = (f16*)(ws);                                   // 4 MB
  f16* kp = (f16*)(ws + (1u << 22));                      // 4 MB
  f16* vpt = (f16*)(ws + (2u << 22));                     // 4 MB [b,h,d,l]
  float* R = (float*)(ws + (3u << 22));                   // 32768*48*4 = 6 MB
  size_t off = (3u << 22) + (size_t)32768 * RS * 4;
  u64* mp64 = (u64*)(ws + off);                           // 1 MB
  f16* concat = (f16*)(ws + off + (1u << 20));            // 4 MB
  f16* WT = (f16*)(ws + off + (1u << 20) + (1u << 22));   // 2 MB
  f16* rpef = (f16*)(ws + off + (1u << 20) + (1u << 22) + (1u << 21));  // 6 KB

  float* final_out = (float*)d_out;
  float* attn_out = final_out + (size_t)BS * LQ * DM;

  prep_k<<<dim3(257), 256, 0, stream>>>(Wq, Wk, Wv, Wo, WT, rpe, rpef);

  qkvm_k<<<dim3(NQKV + BS * LQ * LK / 256), 256, 0, stream>>>(
      q, k, v, WT, rpef, bq, bk, bv, qp, kp, vpt, R, mask, mp64);

  attn_k<<<dim3(512), 512, 0, stream>>>(qp, kp, vpt, R, (const unsigned*)mp64, attn_out,
                                        concat);

  ogemm_k<<<dim3(64, 8), 256, 0, stream>>>(concat, WT, bo, final_out);
}

// Round 24
// 144.299 us; speedup vs baseline: 1.3037x; 1.3037x over previous
//
#include <hip/hip_runtime.h>

#define H_ 8
#define DK 64
#define LQ 2048
#define LK 2048
#define BS 2
#define DM 512

typedef _Float16 f16;
typedef _Float16 f16x8 __attribute__((ext_vector_type(8)));
typedef float f32x4 __attribute__((ext_vector_type(4)));
typedef unsigned long long u64;

#define LS 72   // f16 LDS row stride (144B)
#define PS 40   // f16 LDS row stride for P half-tiles
#define RS 48   // R row stride (f32)

#define NQKV 1536  // qkv blocks in merged kernel; maskpack blocks follow

// Q projection prescale: 1/sqrt(64) * log2(e)  (exp -> exp2 in attn)
#define QSCALE 0.1803368801111204f

// ---------------- prep: W transpose (blocks 0..255) + rpe cvt (block 256) ----------------
__global__ __launch_bounds__(256) void prep_k(const float* __restrict__ Wq,
                                              const float* __restrict__ Wk,
                                              const float* __restrict__ Wv,
                                              const float* __restrict__ Wo,
                                              f16* __restrict__ WT,
                                              const float* __restrict__ rpe,
                                              f16* __restrict__ rpef) {
  __shared__ f16 T[64][LS];
  const int bid = blockIdx.x, tid = threadIdx.x;
  if (bid == 256) {  // ---- rpe cvt+pad: [33][64] f32 -> [48][64] f16 ----
#pragma unroll
    for (int j = 0; j < 12; j++) {
      int idx = tid + j * 256;
      int row = idx >> 6, d = idx & 63;
      rpef[idx] = row < 33 ? (f16)rpe[row * DK + d] : (f16)0.f;
    }
    return;
  }
  // ---- wtr: W[k][n] f32 -> WT[seg][n][k] f16 ----
  const int z = bid >> 6, rem = bid & 63;
  const float* W = z == 0 ? Wq : (z == 1 ? Wk : (z == 2 ? Wv : Wo));
  const int n0 = (rem & 7) * 64, k0 = (rem >> 3) * 64;
  const int r = tid >> 2, cg = tid & 3;
#pragma unroll
  for (int p = 0; p < 4; p++) {
    f32x4 v = *(const f32x4*)(W + (size_t)(k0 + r) * DM + n0 + cg * 16 + p * 4);
#pragma unroll
    for (int j = 0; j < 4; j++) T[cg * 16 + p * 4 + j][r] = (f16)v[j];
  }
  __syncthreads();
  const int n = tid >> 2, kc = tid & 3;
#pragma unroll
  for (int p = 0; p < 2; p++) {
    *(f16x8*)(WT + ((size_t)z * DM + n0 + n) * DM + k0 + kc * 16 + p * 8) =
        *(const f16x8*)&T[n][kc * 16 + p * 8];
  }
}

// ---------------- merged: fused QKV projection GEMM + relR epilogue + maskpack ----------------
__global__ __launch_bounds__(256, 4) void qkvm_k(
    const float* __restrict__ qin, const float* __restrict__ kin, const float* __restrict__ vin,
    const f16* __restrict__ WT, const f16* __restrict__ rpef,
    const float* __restrict__ bq, const float* __restrict__ bk, const float* __restrict__ bv,
    f16* __restrict__ qp, f16* __restrict__ kp, f16* __restrict__ vpt,
    float* __restrict__ R, const int* __restrict__ mask, u64* __restrict__ mp64) {
  const int tid = threadIdx.x;
  if (blockIdx.x >= NQKV) {  // ---- maskpack blocks ----
    size_t t = (size_t)(blockIdx.x - NQKV) * 256 + tid;
    u64 bits = __ballot(mask[t] != 0);
    if ((tid & 63) == 0) mp64[t >> 6] = bits;
    return;
  }
  __shared__ f16 As[64][LS];
  __shared__ f16 Bt[64][LS];
  const int lane = tid & 63, w = tid >> 6;
  const int wr = w >> 1, wc = w & 1, fr = lane & 15, fs = lane >> 4;
  const int m0 = (blockIdx.x & 63) * 64;
  const int n0g = (blockIdx.x >> 6) * 64, seg = n0g >> 9, nn0 = n0g & 511;
  const float* X = seg == 0 ? qin : (seg == 1 ? kin : vin);
  const f16* WTs = WT + (size_t)seg * DM * DM;
  const float* bias = seg == 0 ? bq : (seg == 1 ? bk : bv);
  const float scale = seg == 0 ? QSCALE : 1.0f;

  f32x4 acc[2][2] = {};

  for (int k0 = 0; k0 < DM; k0 += 64) {
    __syncthreads();
    {
      int m = tid >> 2, c0 = tid & 3;
#pragma unroll
      for (int pp = 0; pp < 2; pp++) {
        int cc = c0 + pp * 4;
        const float* p = X + (size_t)(m0 + m) * DM + k0 + cc * 8;
        f32x4 v0 = *(const f32x4*)p;
        f32x4 v1 = *(const f32x4*)(p + 4);
        f16x8 hv;
#pragma unroll
        for (int i = 0; i < 4; i++) { hv[i] = (f16)v0[i]; hv[i + 4] = (f16)v1[i]; }
        *(f16x8*)&As[m][cc * 8] = hv;
      }
      int n = tid >> 2, kc = tid & 3;
#pragma unroll
      for (int pp = 0; pp < 2; pp++) {
        *(f16x8*)&Bt[n][kc * 16 + pp * 8] =
            *(const f16x8*)(WTs + (size_t)(nn0 + n) * DM + k0 + kc * 16 + pp * 8);
      }
    }
    __syncthreads();
#pragma unroll
    for (int kc = 0; kc < 2; kc++) {
      f16x8 a[2], b[2];
#pragma unroll
      for (int mi = 0; mi < 2; mi++)
        a[mi] = *(const f16x8*)&As[wr * 32 + mi * 16 + fr][kc * 32 + fs * 8];
#pragma unroll
      for (int ni = 0; ni < 2; ni++)
        b[ni] = *(const f16x8*)&Bt[wc * 32 + ni * 16 + fr][kc * 32 + fs * 8];
#pragma unroll
      for (int mi = 0; mi < 2; mi++)
#pragma unroll
        for (int ni = 0; ni < 2; ni++)
          acc[mi][ni] = __builtin_amdgcn_mfma_f32_16x16x32_f16(a[mi], b[ni], acc[mi][ni], 0, 0, 0);
    }
  }

  const int h = nn0 >> 6, b_ = m0 >> 11, l0 = m0 & (LQ - 1);
  if (seg < 2) {
    f16* out = seg == 0 ? qp : kp;
    if (seg == 0) __syncthreads();
#pragma unroll
    for (int mi = 0; mi < 2; mi++)
#pragma unroll
      for (int ni = 0; ni < 2; ni++) {
        int d = wc * 32 + ni * 16 + fr;
        float bb = bias[nn0 + d];
#pragma unroll
        for (int i = 0; i < 4; i++) {
          int row = wr * 32 + mi * 16 + fs * 4 + i;
          f16 hv = (f16)((acc[mi][ni][i] + bb) * scale);
          out[((size_t)(b_ * H_ + h) * LQ + l0 + row) * DK + d] = hv;
          if (seg == 0) As[row][d] = hv;
        }
      }
    if (seg == 0) {
      __syncthreads();
      f16x8 a0 = *(const f16x8*)&As[w * 16 + fr][fs * 8];
      f16x8 a1 = *(const f16x8*)&As[w * 16 + fr][32 + fs * 8];
      const size_t rbase = ((size_t)(b_ * H_ + h) * LQ + l0 + w * 16);
#pragma unroll
      for (int nt = 0; nt < 3; nt++) {
        f16x8 b0 = *(const f16x8*)(rpef + (size_t)(nt * 16 + fr) * DK + fs * 8);
        f16x8 b1 = *(const f16x8*)(rpef + (size_t)(nt * 16 + fr) * DK + 32 + fs * 8);
        f32x4 rc = {};
        rc = __builtin_amdgcn_mfma_f32_16x16x32_f16(a0, b0, rc, 0, 0, 0);
        rc = __builtin_amdgcn_mfma_f32_16x16x32_f16(a1, b1, rc, 0, 0, 0);
#pragma unroll
        for (int i = 0; i < 4; i++)
          R[(rbase + fs * 4 + i) * RS + nt * 16 + fr] = rc[i];
      }
    }
  } else {
    __syncthreads();
#pragma unroll
    for (int mi = 0; mi < 2; mi++)
#pragma unroll
      for (int ni = 0; ni < 2; ni++) {
        int d = wc * 32 + ni * 16 + fr;
        float bb = bias[nn0 + d];
#pragma unroll
        for (int i = 0; i < 4; i++) {
          int ml = wr * 32 + mi * 16 + fs * 4 + i;
          As[d][ml] = (f16)(acc[mi][ni][i] + bb);
        }
      }
    __syncthreads();
    int r = tid >> 2;
#pragma unroll
    for (int pp = 0; pp < 2; pp++) {
      int c = (tid & 3) + pp * 4;
      *(f16x8*)(vpt + ((size_t)((b_ * H_ + h) * DK + r)) * LK + l0 + c * 8) =
          *(const f16x8*)&As[r][c * 8];
    }
  }
}

// ---------------- fused attention (R19/R22-proven): sweep1 KBLK=128, sweep2 KBLK=64 ----------------
__global__ __launch_bounds__(512, 4) void attn_k(const f16* __restrict__ qp,
                                                 const f16* __restrict__ kp,
                                                 const f16* __restrict__ vpt,
                                                 const float* __restrict__ R,
                                                 const unsigned* __restrict__ mp,
                                                 float* __restrict__ attn,
                                                 f16* __restrict__ concat) {
  __shared__ f16 Ks[64][LS];       // K-tile [k][d]
  __shared__ f16 Vt[64][LS];       // V-tile [d][k] in sweep 2; K rows 64..127 in sweep 1
  __shared__ f16 Pl[8][16][PS];    // per-wave P half-tile [q][k-half]
  __shared__ float Rl[64][34];
  __shared__ float Ph[2][64];      // psum halves
  __shared__ float Oc[4][16][68];  // oacc combine (wh=1 -> wh=0)
  const int tid = threadIdx.x, lane = tid & 63, w = tid >> 6;
  const int wq = w & 3, wh = w >> 2;
  const int fr = lane & 15, fs = lane >> 4;
  const int flat = blockIdx.x;
  const int idx = flat >> 3;
  const int bh = (flat & 7) * 2 + (idx >> 5), q0 = (idx & 31) * 64;
  const int b = bh >> 3, h = bh & 7;
  const f16* Qb = qp + ((size_t)bh * LQ + q0) * DK;
  const f16* Kb = kp + (size_t)bh * LQ * DK;
  const f16* Vb = vpt + (size_t)bh * DK * LK;

  for (int i2 = tid; i2 < 64 * 34; i2 += 512)
    Rl[i2 / 34][i2 % 34] = R[((size_t)bh * LQ + q0 + i2 / 34) * RS + i2 % 34];
  __syncthreads();

  f16x8 qa[2];
#pragma unroll
  for (int h2 = 0; h2 < 2; h2++)
    qa[h2] = *(const f16x8*)(Qb + (size_t)(wq * 16 + fr) * DK + h2 * 32 + fs * 8);

  int qq[4];
  float rlo[4], rhi[4];
  const unsigned* mprow[4];
#pragma unroll
  for (int i = 0; i < 4; i++) {
    qq[i] = wq * 16 + fs * 4 + i;
    rlo[i] = Rl[qq[i]][0];
    rhi[i] = Rl[qq[i]][32];
    mprow[i] = mp + ((size_t)b * LQ + q0 + qq[i]) * 64;
  }

  // ---- sweep 1: denominator (KBLK=128: stage 128 K rows, 2 subtiles per barrier) ----
  float psum[4] = {0.f, 0.f, 0.f, 0.f};
  for (int kt = 0; kt < LK; kt += 128) {
    __syncthreads();
    {
      int r = tid >> 3, c = tid & 7;
      *(f16x8*)&Ks[r][c * 8] = *(const f16x8*)(Kb + (size_t)(kt + r) * DK + c * 8);
      *(f16x8*)&Vt[r][c * 8] = *(const f16x8*)(Kb + (size_t)(kt + 64 + r) * DK + c * 8);
    }
    __syncthreads();
#pragma unroll
    for (int half = 0; half < 2; half++) {
      const int kb = kt + half * 64;
      f32x4 sv[2];
#pragma unroll
      for (int cbh = 0; cbh < 2; cbh++) {
        int cb = wh * 2 + cbh;
        f32x4 s = {};
#pragma unroll
        for (int h2 = 0; h2 < 2; h2++) {
          f16x8 bf = half == 0 ? *(const f16x8*)&Ks[cb * 16 + fr][h2 * 32 + fs * 8]
                               : *(const f16x8*)&Vt[cb * 16 + fr][h2 * 32 + fs * 8];
          s = __builtin_amdgcn_mfma_f32_16x16x32_f16(qa[h2], bf, s, 0, 0, 0);
        }
        sv[cbh] = s;
      }
      unsigned mw[4];
#pragma unroll
      for (int i = 0; i < 4; i++) mw[i] = mprow[i][(kb >> 5) + wh];
      const int dt = kb - q0;
      if (dt <= -128 || dt >= 128) {
#pragma unroll
        for (int cbh = 0; cbh < 2; cbh++)
#pragma unroll
          for (int i = 0; i < 4; i++) {
            float sc = sv[cbh][i] + (dt < 0 ? rlo[i] : rhi[i]);
            psum[i] += ((mw[i] >> (cbh * 16 + fr)) & 1u) ? exp2f(sc) : 0.f;
          }
      } else {
#pragma unroll
        for (int cbh = 0; cbh < 2; cbh++)
#pragma unroll
          for (int i = 0; i < 4; i++) {
            int dd = dt + wh * 32 + cbh * 16 + fr - qq[i];
            dd = dd < -16 ? -16 : (dd > 16 ? 16 : dd);
            float sc = sv[cbh][i] + Rl[qq[i]][dd + 16];
            psum[i] += ((mw[i] >> (cbh * 16 + fr)) & 1u) ? exp2f(sc) : 0.f;
          }
      }
    }
  }
#pragma unroll
  for (int i = 0; i < 4; i++) {
    float v = psum[i];
    v += __shfl_xor(v, 1);
    v += __shfl_xor(v, 2);
    v += __shfl_xor(v, 4);
    v += __shfl_xor(v, 8);
    psum[i] = v;
  }
  if (fr == 0)
#pragma unroll
    for (int i = 0; i < 4; i++) Ph[wh][qq[i]] = psum[i];
  __syncthreads();
  float inv[4];
#pragma unroll
  for (int i = 0; i < 4; i++) inv[i] = 1.f / (Ph[0][qq[i]] + Ph[1][qq[i]]);

  // ---- sweep 2: recompute, write normalized attn, accumulate PV (KBLK=64) ----
  f32x4 oacc[4] = {};
  for (int kt = 0; kt < LK; kt += 64) {
    __syncthreads();
    {
      int r = tid >> 3, c = tid & 7;
      *(f16x8*)&Ks[r][c * 8] = *(const f16x8*)(Kb + (size_t)(kt + r) * DK + c * 8);
      *(f16x8*)&Vt[r][c * 8] = *(const f16x8*)(Vb + (size_t)r * LK + kt + c * 8);
    }
    __syncthreads();
    f32x4 sv[2];
#pragma unroll
    for (int cbh = 0; cbh < 2; cbh++) {
      int cb = wh * 2 + cbh;
      f32x4 s = {};
#pragma unroll
      for (int h2 = 0; h2 < 2; h2++) {
        f16x8 bf = *(const f16x8*)&Ks[cb * 16 + fr][h2 * 32 + fs * 8];
        s = __builtin_amdgcn_mfma_f32_16x16x32_f16(qa[h2], bf, s, 0, 0, 0);
      }
      sv[cbh] = s;
    }
    unsigned mw[4];
#pragma unroll
    for (int i = 0; i < 4; i++) mw[i] = mprow[i][(kt >> 5) + wh];
    const int dt = kt - q0;
    if (dt <= -128 || dt >= 128) {
#pragma unroll
      for (int cbh = 0; cbh < 2; cbh++)
#pragma unroll
        for (int i = 0; i < 4; i++) {
          float sc = sv[cbh][i] + (dt < 0 ? rlo[i] : rhi[i]);
          float pv = ((mw[i] >> (cbh * 16 + fr)) & 1u) ? exp2f(sc) * inv[i] : 0.f;
          Pl[w][fs * 4 + i][cbh * 16 + fr] = (f16)pv;
        }
    } else {
#pragma unroll
      for (int cbh = 0; cbh < 2; cbh++)
#pragma unroll
        for (int i = 0; i < 4; i++) {
          int dd = dt + wh * 32 + cbh * 16 + fr - qq[i];
          dd = dd < -16 ? -16 : (dd > 16 ? 16 : dd);
          float sc = sv[cbh][i] + Rl[qq[i]][dd + 16];
          float pv = ((mw[i] >> (cbh * 16 + fr)) & 1u) ? exp2f(sc) * inv[i] : 0.f;
          Pl[w][fs * 4 + i][cbh * 16 + fr] = (f16)pv;
        }
    }
    // PV over this wave's 32-k half (wave-private Pl)
    {
      f16x8 pa = *(const f16x8*)&Pl[w][fr][fs * 8];
#pragma unroll
      for (int db = 0; db < 4; db++) {
        f16x8 vb = *(const f16x8*)&Vt[db * 16 + fr][wh * 32 + fs * 8];
        oacc[db] = __builtin_amdgcn_mfma_f32_16x16x32_f16(pa, vb, oacc[db], 0, 0, 0);
      }
    }
    // coalesced attn write from Pl (f32x4, non-temporal)
    {
      int r2 = lane >> 2, cq = lane & 3;
      float* arow = attn + ((size_t)bh * LQ + q0 + wq * 16 + r2) * LK + kt + wh * 32 + cq * 8;
      f16x8 pv8 = *(const f16x8*)&Pl[w][r2][cq * 8];
      f32x4 o0 = {(float)pv8[0], (float)pv8[1], (float)pv8[2], (float)pv8[3]};
      f32x4 o1 = {(float)pv8[4], (float)pv8[5], (float)pv8[6], (float)pv8[7]};
      __builtin_nontemporal_store(o0, (f32x4*)arow);
      __builtin_nontemporal_store(o1, (f32x4*)(arow + 4));
    }
  }

  // combine oacc across k-halves, write concat (f16 [b, l, h*64+d])
  __syncthreads();
  if (wh == 1) {
#pragma unroll
    for (int db = 0; db < 4; db++)
#pragma unroll
      for (int i = 0; i < 4; i++) Oc[wq][fs * 4 + i][db * 16 + fr] = oacc[db][i];
  }
  __syncthreads();
  if (wh == 0) {
#pragma unroll
    for (int db = 0; db < 4; db++)
#pragma unroll
      for (int i = 0; i < 4; i++) {
        float val = oacc[db][i] + Oc[wq][fs * 4 + i][db * 16 + fr];
        int gq = q0 + wq * 16 + fs * 4 + i;
        concat[((size_t)b * LQ + gq) * DM + h * DK + db * 16 + fr] = (f16)val;
      }
  }
}

// ---------------- output GEMM (B from WT seg 3, plain stores) ------
__global__ __launch_bounds__(256, 4) void ogemm_k(const f16* __restrict__ X,
                                                  const f16* __restrict__ WT,
                                                  const float* __restrict__ bias,
                                                  float* __restrict__ out) {
  __shared__ f16 As[64][LS];
  __shared__ f16 Bt[64][LS];
  const int tid = threadIdx.x, lane = tid & 63, w = tid >> 6;
  const int wr = w >> 1, wc = w & 1, fr = lane & 15, fs = lane >> 4;
  const int m0 = blockIdx.x * 64, n0 = blockIdx.y * 64;
  const f16* WTo = WT + (size_t)3 * DM * DM;

  f32x4 acc[2][2] = {};
  for (int k0 = 0; k0 < DM; k0 += 64) {
    __syncthreads();
    {
      int r = tid >> 2, c0 = tid & 3;
#pragma unroll
      for (int pp = 0; pp < 2; pp++) {
        int c = c0 + pp * 4;
        *(f16x8*)&As[r][c * 8] = *(const f16x8*)(X + (size_t)(m0 + r) * DM + k0 + c * 8);
      }
      int n = tid >> 2, kc = tid & 3;
#pragma unroll
      for (int pp = 0; pp < 2; pp++) {
        *(f16x8*)&Bt[n][kc * 16 + pp * 8] =
            *(const f16x8*)(WTo + (size_t)(n0 + n) * DM + k0 + kc * 16 + pp * 8);
      }
    }
    __syncthreads();
#pragma unroll
    for (int kc = 0; kc < 2; kc++) {
      f16x8 a[2], b[2];
#pragma unroll
      for (int mi = 0; mi < 2; mi++)
        a[mi] = *(const f16x8*)&As[wr * 32 + mi * 16 + fr][kc * 32 + fs * 8];
#pragma unroll
      for (int ni = 0; ni < 2; ni++)
        b[ni] = *(const f16x8*)&Bt[wc * 32 + ni * 16 + fr][kc * 32 + fs * 8];
#pragma unroll
      for (int mi = 0; mi < 2; mi++)
#pragma unroll
        for (int ni = 0; ni < 2; ni++)
          acc[mi][ni] = __builtin_amdgcn_mfma_f32_16x16x32_f16(a[mi], b[ni], acc[mi][ni], 0, 0, 0);
    }
  }
#pragma unroll
  for (int mi = 0; mi < 2; mi++)
#pragma unroll
    for (int ni = 0; ni < 2; ni++) {
      int gcol = n0 + wc * 32 + ni * 16 + fr;
      float bb = bias[gcol];
#pragma unroll
      for (int i = 0; i < 4; i++) {
        int grow = m0 + wr * 32 + mi * 16 + fs * 4 + i;
        out[(size_t)grow * DM + gcol] = acc[mi][ni][i] + bb;
      }
    }
}

extern "C" void kernel_launch(void* const* d_in, const int* in_sizes, int n_in,
                              void* d_out, int out_size, void* d_ws, size_t ws_size,
                              hipStream_t stream) {
  const float* q = (const float*)d_in[0];
  const float* k = (const float*)d_in[1];
  const float* v = (const float*)d_in[2];
  const int* mask = (const int*)d_in[3];
  const float* Wq = (const float*)d_in[4];
  const float* bq = (const float*)d_in[5];
  const float* Wk = (const float*)d_in[6];
  const float* bk = (const float*)d_in[7];
  const float* Wv = (const float*)d_in[8];
  const float* bv = (const float*)d_in[9];
  const float* Wo = (const float*)d_in[10];
  const float* bo = (const float*)d_in[11];
  const float* rpe = (const float*)d_in[12];

  char* ws = (char*)d_ws;
  f16* qp = (f16*)(ws);                                   // 4 MB
  f16* kp = (f16*)(ws + (1u << 22));                      // 4 MB
  f16* vpt = (f16*)(ws + (2u << 22));                     // 4 MB [b,h,d,l]
  float* R = (float*)(ws + (3u << 22));                   // 32768*48*4 = 6 MB
  size_t off = (3u << 22) + (size_t)32768 * RS * 4;
  u64* mp64 = (u64*)(ws + off);                           // 1 MB
  f16* concat = (f16*)(ws + off + (1u << 20));            // 4 MB
  f16* WT = (f16*)(ws + off + (1u << 20) + (1u << 22));   // 2 MB
  f16* rpef = (f16*)(ws + off + (1u << 20) + (1u << 22) + (1u << 21));  // 6 KB

  float* final_out = (float*)d_out;
  float* attn_out = final_out + (size_t)BS * LQ * DM;

  prep_k<<<dim3(257), 256, 0, stream>>>(Wq, Wk, Wv, Wo, WT, rpe, rpef);

  qkvm_k<<<dim3(NQKV + BS * LQ * LK / 256), 256, 0, stream>>>(
      q, k, v, WT, rpef, bq, bk, bv, qp, kp, vpt, R, mask, mp64);

  attn_k<<<dim3(512), 512, 0, stream>>>(qp, kp, vpt, R, (const unsigned*)mp64, attn_out,
                                        concat);

  ogemm_k<<<dim3(64, 8), 256, 0, stream>>>(concat, WT, bo, final_out);
}